// Round 16
// baseline (230.848 us; speedup 1.0000x reference)
//
#include <hip/hip_runtime.h>
#include <hip/hip_fp16.h>
#include <math.h>

// rbfLayer: N=100k points, DEG=16 neighbors, NB=MB=4 bases, FIN=FOUT=8.
// out[u,i] = sum_{e,n,m,j} c_e[n] f_e[m] K[i,j,n,m] feat[nbr_e, j]
// R15 established: packed-FMA halved VALU (-10us). R16: 8 threads/point
// (j-half x eh-quarter, 4 edges/thread) to double wave supply 24->32/CU
// (grid was work-limited, not capacity-limited). One-time butterfly
// g-reduce across eh lanes (shfl_xor 2,4 -- epilogue, NOT in edge loop),
// then contraction split 4-ways (each lane computes 2 of 8 outputs) so
// total contraction MACs/point are unchanged and LDS reads halve.
// __launch_bounds__(256,8) forces VGPR<=64 for 8 waves/SIMD.

#define TWO_OVER_PI 0.63661977236758134f

typedef float v2f __attribute__((ext_vector_type(2)));

__device__ __forceinline__ float fast_atan2f(float y, float x) {
    float ax = fabsf(x), ay = fabsf(y);
    float mx = fmaxf(ax, ay);
    float mn = fminf(ax, ay);
    mx = fmaxf(mx, 1e-30f);                      // guard rcp(0)
    float r = mn * __builtin_amdgcn_rcpf(mx);
    float s = r * r;
    float p = -0.0117212f;                       // minimax atan on [0,1]
    p = fmaf(p, s,  0.05265332f);
    p = fmaf(p, s, -0.11643287f);
    p = fmaf(p, s,  0.19354346f);
    p = fmaf(p, s, -0.33262347f);
    p = fmaf(p, s,  0.99997726f);
    float a = p * r;
    a = (ay > ax) ? (1.57079632679f - a) : a;    // fold octant
    a = (x < 0.0f) ? (3.14159265359f - a) : a;   // fold quadrant
    return copysignf(a, y);
}

__device__ __forceinline__ void edge_basis(float dx, float dy,
                                           float c[4], float f[4]) {
    float dist = sqrtf(fmaf(dx, dx, dy * dy));
    float tr = dist * 1.5f;                       // radial hat coordinate
    float theta = fast_atan2f(dy, dx);
    float ta = fmaf(theta, TWO_OVER_PI, 2.0f);    // angular in [0,4]
#pragma unroll
    for (int n = 0; n < 4; ++n)
        c[n] = fmaxf(1.0f - fabsf(tr - (float)n), 0.0f);
#pragma unroll
    for (int m = 0; m < 4; ++m) {
        float d = fabsf(ta - (float)m);
        d = fminf(d, 4.0f - d);                   // periodic wrap (period 4)
        f[m] = fmaxf(1.0f - d, 0.0f);
    }
}

__device__ __forceinline__ float2 h2f(float bits) {
    union { float f; __half2 h; } u;
    u.f = bits;
    return make_float2(__low2float(u.h), __high2float(u.h));
}

__device__ __forceinline__ float h2f_pack(float a, float b) {
    union { __half2 h; float f; } u;
    u.h = __floats2half2_rn(a, b);
    return u.f;
}

__device__ __forceinline__ v2f shfl_xor_v2(v2f v, int mask) {
    v2f r;
    r.x = __shfl_xor(v.x, mask);
    r.y = __shfl_xor(v.y, mask);
    return r;
}

// ---- Pre-pass: self-contained 16B halves, positions duplicated.
__global__ __launch_bounds__(256) void pack_kernel(
    const float* __restrict__ positions,
    const float* __restrict__ features,
    float4*      __restrict__ packed,    // 2 float4 per point (32B record)
    int npts)
{
    int u = blockIdx.x * blockDim.x + threadIdx.x;
    if (u >= npts) return;
    float2 p  = ((const float2*)positions)[u];
    float4 fa = ((const float4*)features)[u * 2];
    float4 fb = ((const float4*)features)[u * 2 + 1];
    float4 q0, q1;
    q0.x = p.x;
    q0.y = p.y;
    q0.z = h2f_pack(fa.x, fa.y);
    q0.w = h2f_pack(fa.z, fa.w);
    q1.x = p.x;
    q1.y = p.y;
    q1.z = h2f_pack(fb.x, fb.y);
    q1.w = h2f_pack(fb.z, fb.w);
    packed[u * 2]     = q0;
    packed[u * 2 + 1] = q1;
}

// ---- Main kernel: 8 threads/point, butterfly g-reduce, split contraction.
__global__ __launch_bounds__(256, 8) void rbf_packed_kernel(
    const float* __restrict__ positions,
    const float4* __restrict__ packed,
    const float* __restrict__ kern,
    const int*   __restrict__ neighbors,
    const int*   __restrict__ row_splits,
    float*       __restrict__ out,
    int npts)
{
    __shared__ float Kl[1024];   // K[i][j][n][m], i*128 + j*16 + n*4 + m
    {
        const float4* src = (const float4*)kern;
        float4* dst = (float4*)Kl;
        dst[threadIdx.x] = src[threadIdx.x];
    }
    __syncthreads();

    int gt   = blockIdx.x * blockDim.x + threadIdx.x;
    int u    = gt >> 3;
    int sub  = gt & 7;
    int half = sub & 1;      // j-half: feature/K columns [half*4, half*4+4)
    int eh   = sub >> 1;     // edge-quarter: edges [rs0+eh*4, rs0+eh*4+4)
    if (u >= npts) return;

    float2 pu = ((const float2*)positions)[u];
    int rs0 = row_splits[u];
    int rs1 = row_splits[u + 1];
    int cnt = rs1 - rs0;

    // g2[j][p] = { G[2p][j], G[2p+1][j] },  p = adjacent-nm pair (0..7)
    v2f g2[4][8];
#pragma unroll
    for (int j = 0; j < 4; ++j)
#pragma unroll
        for (int p = 0; p < 8; ++p) g2[j][p] = (v2f){0.0f, 0.0f};

#define VISIT(R)                                                              \
    {                                                                         \
        float c[4], f[4];                                                     \
        edge_basis(R.x - pu.x, R.y - pu.y, c, f);                             \
        v2f f2[2] = { {f[0], f[1]}, {f[2], f[3]} };                           \
        float2 lo = h2f(R.z);                                                 \
        float2 hi = h2f(R.w);                                                 \
        float fvj[4] = {lo.x, lo.y, hi.x, hi.y};                              \
        _Pragma("unroll")                                                     \
        for (int n = 0; n < 4; ++n) {                                         \
            _Pragma("unroll")                                                 \
            for (int mh = 0; mh < 2; ++mh) {                                  \
                v2f w2 = c[n] * f2[mh];          /* 1 pk_mul */               \
                _Pragma("unroll")                                             \
                for (int j = 0; j < 4; ++j) {                                 \
                    v2f fb = { fvj[j], fvj[j] };                              \
                    g2[j][n * 2 + mh] =                                       \
                        __builtin_elementwise_fma(w2, fb, g2[j][n * 2 + mh]); \
                }                                                             \
            }                                                                 \
        }                                                                     \
    }

    if (cnt == 16) {
        int e0 = rs0 + eh * 4;
        int4 nb = *(const int4*)(neighbors + e0);
        // 4 self-contained record loads issued before compute; half-pair
        // lanes hit the same 64B line (1 line/edge).
        float4 R0 = packed[nb.x * 2 + half];
        float4 R1 = packed[nb.y * 2 + half];
        float4 R2 = packed[nb.z * 2 + half];
        float4 R3 = packed[nb.w * 2 + half];
        VISIT(R0)
        VISIT(R1)
        VISIT(R2)
        VISIT(R3)
    } else {
        // Generic path (uniform DEG=16 never takes this; kept for safety).
        int cq = (cnt + 3) >> 2;
        int e0 = rs0 + eh * cq;
        int e1 = e0 + cq;
        if (e1 > rs1) e1 = rs1;
        for (int e = e0; e < e1; ++e) {
            int nb = neighbors[e];
            float4 R = packed[nb * 2 + half];
            VISIT(R)
        }
    }
#undef VISIT

    // Butterfly g-reduce across the 4 eh lanes (sub bits 1,2). One-time,
    // epilogue-class (NOT in the edge loop -- R5/R8 lesson applies to the
    // per-edge critical path only). After this every lane holds the
    // eh-complete G for its j-half.
#pragma unroll
    for (int j = 0; j < 4; ++j)
#pragma unroll
        for (int p = 0; p < 8; ++p) {
            g2[j][p] += shfl_xor_v2(g2[j][p], 2);
            g2[j][p] += shfl_xor_v2(g2[j][p], 4);
        }

    // Split contraction: this lane computes outputs i0, i0+1 over its j-half.
    int i0 = eh * 2;
    const float4* K4 = (const float4*)Kl;
    float o[2];
#pragma unroll
    for (int t = 0; t < 2; ++t) {
        int i = i0 + t;
        v2f acc = (v2f){0.0f, 0.0f};
#pragma unroll
        for (int j = 0; j < 4; ++j) {
            int jg = half * 4 + j;
            int base4 = (i * 128 + jg * 16) >> 2;
#pragma unroll
            for (int q = 0; q < 4; ++q) {
                float4 kv = K4[base4 + q];
                v2f klo = { kv.x, kv.y };
                v2f khi = { kv.z, kv.w };
                acc = __builtin_elementwise_fma(klo, g2[j][2 * q],     acc);
                acc = __builtin_elementwise_fma(khi, g2[j][2 * q + 1], acc);
            }
        }
        o[t] = acc.x + acc.y;
    }

    // Combine the two j-halves (lane pair, sub bit 0), then store.
    o[0] += __shfl_xor(o[0], 1);
    o[1] += __shfl_xor(o[1], 1);
    if (half == 0)
        ((float2*)out)[u * 4 + eh] = make_float2(o[0], o[1]);
}

// ---- Fallback (no workspace): direct gathers, full fp32 (4 threads/point).
__global__ __launch_bounds__(256) void rbf_direct_kernel(
    const float* __restrict__ positions,
    const float* __restrict__ features,
    const float* __restrict__ kern,
    const int*   __restrict__ neighbors,
    const int*   __restrict__ row_splits,
    float*       __restrict__ out,
    int npts)
{
    __shared__ float Kl[1024];
    {
        const float4* src = (const float4*)kern;
        float4* dst = (float4*)Kl;
        dst[threadIdx.x] = src[threadIdx.x];
    }
    __syncthreads();

    int gt   = blockIdx.x * blockDim.x + threadIdx.x;
    int u    = gt >> 2;
    int sub  = gt & 3;
    int half = sub & 1;
    int eh   = sub >> 1;
    if (u >= npts) return;

    float2 pu = ((const float2*)positions)[u];
    int rs0 = row_splits[u];
    int rs1 = row_splits[u + 1];
    int cnt = rs1 - rs0;

    float g[16][4];
#pragma unroll
    for (int nm = 0; nm < 16; ++nm)
#pragma unroll
        for (int j = 0; j < 4; ++j) g[nm][j] = 0.0f;

    const float2* pos2  = (const float2*)positions;
    const float4* feat4 = (const float4*)features;

    int c0 = (cnt + 1) >> 1;
    int e0 = rs0 + eh * c0;
    int e1 = (eh == 0) ? (rs0 + c0) : rs1;
    for (int e = e0; e < e1; ++e) {
        int nb = neighbors[e];
        float2 pn = pos2[nb];
        float c[4], f[4];
        edge_basis(pn.x - pu.x, pn.y - pu.y, c, f);
        float4 fv = feat4[nb * 2 + half];
        float fvj[4] = {fv.x, fv.y, fv.z, fv.w};
#pragma unroll
        for (int n = 0; n < 4; ++n)
#pragma unroll
            for (int m = 0; m < 4; ++m) {
                float w = c[n] * f[m];
#pragma unroll
                for (int j = 0; j < 4; ++j)
                    g[n * 4 + m][j] = fmaf(w, fvj[j], g[n * 4 + m][j]);
            }
    }

    float o[8];
#pragma unroll
    for (int i = 0; i < 8; ++i) o[i] = 0.0f;
    const float4* K4 = (const float4*)Kl;
#pragma unroll
    for (int i = 0; i < 8; ++i) {
#pragma unroll
        for (int j = 0; j < 4; ++j) {
            int jg = half * 4 + j;
            int base4 = (i * 128 + jg * 16) >> 2;
#pragma unroll
            for (int q = 0; q < 4; ++q) {
                float4 kv = K4[base4 + q];
                o[i] = fmaf(kv.x, g[q * 4 + 0][j], o[i]);
                o[i] = fmaf(kv.y, g[q * 4 + 1][j], o[i]);
                o[i] = fmaf(kv.z, g[q * 4 + 2][j], o[i]);
                o[i] = fmaf(kv.w, g[q * 4 + 3][j], o[i]);
            }
        }
    }
#pragma unroll
    for (int i = 0; i < 8; ++i) {
        o[i] += __shfl_xor(o[i], 1);
        o[i] += __shfl_xor(o[i], 2);
    }
    float2 ov = (sub == 0) ? make_float2(o[0], o[1])
              : (sub == 1) ? make_float2(o[2], o[3])
              : (sub == 2) ? make_float2(o[4], o[5])
                           : make_float2(o[6], o[7]);
    ((float2*)out)[u * 4 + sub] = ov;
}

extern "C" void kernel_launch(void* const* d_in, const int* in_sizes, int n_in,
                              void* d_out, int out_size, void* d_ws, size_t ws_size,
                              hipStream_t stream) {
    const float* positions  = (const float*)d_in[0];
    const float* features   = (const float*)d_in[1];
    const float* kern       = (const float*)d_in[2];
    const int*   neighbors  = (const int*)d_in[3];
    const int*   row_splits = (const int*)d_in[4];
    float* out = (float*)d_out;

    int npts = in_sizes[0] / 2;
    int block = 256;

    size_t need = (size_t)npts * 32;   // 32B packed record per point
    if (ws_size >= need) {
        int pgrid = (npts + block - 1) / block;
        pack_kernel<<<pgrid, block, 0, stream>>>(positions, features,
                                                 (float4*)d_ws, npts);
        int total = npts * 8;
        int grid = (total + block - 1) / block;
        rbf_packed_kernel<<<grid, block, 0, stream>>>(positions,
                                                      (const float4*)d_ws, kern,
                                                      neighbors, row_splits,
                                                      out, npts);
    } else {
        int total = npts * 4;
        int grid = (total + block - 1) / block;
        rbf_direct_kernel<<<grid, block, 0, stream>>>(positions, features, kern,
                                                      neighbors, row_splits,
                                                      out, npts);
    }
}